// Round 7
// baseline (696.804 us; speedup 1.0000x reference)
//
#include <hip/hip_runtime.h>
#include <hip/hip_bf16.h>

#define N_NODES 100000
#define NEDGE   600000
#define SCAN_B  1024
#define NBLK    98            // ceil(N_NODES / SCAN_B)
#define XRANGE  12500         // N_NODES / 8 (per-XCD dst range)
#define SEGCAP  81920         // per (rel,class) staging capacity (75000 + 27 sigma)
#define BINK    40            // SEGCAP / 2048

typedef __attribute__((ext_vector_type(8))) short bf16x8;
typedef __attribute__((ext_vector_type(4))) short s16x4;
typedef __attribute__((ext_vector_type(4))) float f32x4;
typedef __attribute__((ext_vector_type(4))) unsigned u32x4;
typedef __attribute__((ext_vector_type(2))) int int2v;

__device__ __forceinline__ short f2bf(float f) {
  union { float f; unsigned u; } x; x.f = f;
  unsigned r = x.u + 0x7FFFu + ((x.u >> 16) & 1u);
  return (short)(r >> 16);
}

// Phase A: bin edges into 8 per-class segments of (src,dst) pairs.
// Coalesced read of edge data, segment-contiguous writes (L2-friendly).
__global__ __launch_bounds__(256) void bin_k(const int* __restrict__ sidx,
                                             const int* __restrict__ didx,
                                             int* __restrict__ bincnt,
                                             int2v* __restrict__ stage) {
  __shared__ int hist[8];
  __shared__ int base[8];
  int r = blockIdx.y, t = threadIdx.x;
  int e0 = blockIdx.x * 2048 + t;
  const int* dd = didx + (size_t)r * NEDGE;
  const int* ss = sidx + (size_t)r * NEDGE;
  if (t < 8) hist[t] = 0;
  __syncthreads();
  int sv[8], dv[8], cv[8], lr[8];
#pragma unroll
  for (int j = 0; j < 8; ++j) {
    int e = e0 + j * 256;
    if (e < NEDGE) {
      dv[j] = dd[e]; sv[j] = ss[e];
      cv[j] = dv[j] / XRANGE;
      lr[j] = atomicAdd(&hist[cv[j]], 1);
    }
  }
  __syncthreads();
  if (t < 8) base[t] = atomicAdd(&bincnt[r * 8 + t], hist[t]);
  __syncthreads();
#pragma unroll
  for (int j = 0; j < 8; ++j) {
    int e = e0 + j * 256;
    if (e < NEDGE)
      stage[(size_t)(r * 8 + cv[j]) * SEGCAP + base[cv[j]] + lr[j]] =
          (int2v){sv[j], dv[j]};
  }
}

// Phase B: XCD-local degree count from staged segment (class g on XCD g;
// reads ONLY its own coalesced segment -> no streaming eviction).
__global__ __launch_bounds__(256) void count2_k(const int2v* __restrict__ stage,
                                                const int* __restrict__ bincnt,
                                                int* __restrict__ cnt) {
  int g = blockIdx.x & 7, k = blockIdx.x >> 3, r = blockIdx.y;
  int len = bincnt[r * 8 + g];
  const int2v* sg = stage + (size_t)(r * 8 + g) * SEGCAP;
  int* cn = cnt + r * N_NODES;
  int i0 = k * 2048 + threadIdx.x;
#pragma unroll
  for (int j = 0; j < 8; ++j) {
    int i = i0 + j * 256;
    if (i < len) atomicAdd(&cn[sg[i].y], 1);
  }
}

// Phase 1: per-block chunk sums. grid (NBLK, 4), 256 thr, 4 elems/thr.
__global__ __launch_bounds__(256) void scan1_k(const int* __restrict__ cnt,
                                               int* __restrict__ bsum) {
  __shared__ int lds[256];
  int b = blockIdx.x, r = blockIdx.y, t = threadIdx.x;
  int i0 = b * SCAN_B + t * 4;
  int s = 0;
#pragma unroll
  for (int j = 0; j < 4; ++j)
    if (i0 + j < N_NODES) s += cnt[r * N_NODES + i0 + j];
  lds[t] = s;
  __syncthreads();
  for (int st = 128; st > 0; st >>= 1) {
    if (t < st) lds[t] += lds[t + st];
    __syncthreads();
  }
  if (t == 0) bsum[r * NBLK + b] = lds[0];
}

// Phase 2: exclusive scan of the NBLK block sums per relation. 1 block, 128 thr.
__global__ __launch_bounds__(128) void scan2_k(int* __restrict__ bsum) {
  __shared__ int buf[128];
  int t = threadIdx.x;
  for (int r = 0; r < 4; ++r) {
    int v = (t < NBLK) ? bsum[r * NBLK + t] : 0;
    buf[t] = v;
    __syncthreads();
    for (int st = 1; st < 128; st <<= 1) {
      int x = (t >= st) ? buf[t - st] : 0;
      __syncthreads();
      buf[t] += x;
      __syncthreads();
    }
    if (t < NBLK) bsum[r * NBLK + t] = buf[t] - v;   // exclusive
    __syncthreads();
  }
}

// Phase 3: local exclusive scan + block base -> off. grid (NBLK, 4), 256 thr.
__global__ __launch_bounds__(256) void scan3_k(const int* __restrict__ cnt,
                                               const int* __restrict__ bsum,
                                               int* __restrict__ off) {
  __shared__ int lds[256];
  int b = blockIdx.x, r = blockIdx.y, t = threadIdx.x;
  int i0 = b * SCAN_B + t * 4;
  int c[4] = {0, 0, 0, 0};
#pragma unroll
  for (int j = 0; j < 4; ++j)
    if (i0 + j < N_NODES) c[j] = cnt[r * N_NODES + i0 + j];
  int s = c[0] + c[1] + c[2] + c[3];
  lds[t] = s;
  __syncthreads();
  for (int st = 1; st < 256; st <<= 1) {
    int x = (t >= st) ? lds[t - st] : 0;
    __syncthreads();
    lds[t] += x;
    __syncthreads();
  }
  int run = bsum[r * NBLK + b] + lds[t] - s;
  int* o = off + r * (N_NODES + 1);
#pragma unroll
  for (int j = 0; j < 4; ++j) {
    if (i0 + j < N_NODES) { o[i0 + j] = run; run += c[j]; }
  }
  if (b == 0 && t == 0) o[N_NODES] = NEDGE;
}

// Phase C: XCD-local CSR place from staged segment. Cursor atomics and csr
// scattered writes stay in one XCD's L2; only coalesced own-segment reads.
__global__ __launch_bounds__(256) void fill2_k(const int2v* __restrict__ stage,
                                               const int* __restrict__ bincnt,
                                               const int* __restrict__ off,
                                               int* __restrict__ cursor,
                                               int* __restrict__ csr) {
  int g = blockIdx.x & 7, k = blockIdx.x >> 3, r = blockIdx.y;
  int len = bincnt[r * 8 + g];
  const int2v* sg = stage + (size_t)(r * 8 + g) * SEGCAP;
  const int* of = off + r * (N_NODES + 1);
  int* cu = cursor + r * N_NODES;
  int* cs = csr + (size_t)r * NEDGE;
  int i0 = k * 2048 + threadIdx.x;
#pragma unroll
  for (int j = 0; j < 8; ++j) {
    int i = i0 + j * 256;
    if (i < len) {
      int2v sd = sg[i];
      int pos = of[sd.y] + atomicAdd(&cu[sd.y], 1);
      cs[pos] = sd.x;
    }
  }
}

// f32 -> packed bf16 (2 per u32); each thread converts 8 floats.
__global__ __launch_bounds__(256) void cvt_bf16_k(const float* __restrict__ x,
                                                  unsigned* __restrict__ o) {
  int i = blockIdx.x * 256 + threadIdx.x;     // i < N_NODES*16
  if (i >= N_NODES * 16) return;
  f32x4 v0 = ((const f32x4*)x)[i * 2];
  f32x4 v1 = ((const f32x4*)x)[i * 2 + 1];
  unsigned r0 = (unsigned)(unsigned short)f2bf(v0[0]) |
                ((unsigned)(unsigned short)f2bf(v0[1]) << 16);
  unsigned r1 = (unsigned)(unsigned short)f2bf(v0[2]) |
                ((unsigned)(unsigned short)f2bf(v0[3]) << 16);
  unsigned r2 = (unsigned)(unsigned short)f2bf(v1[0]) |
                ((unsigned)(unsigned short)f2bf(v1[1]) << 16);
  unsigned r3 = (unsigned)(unsigned short)f2bf(v1[2]) |
                ((unsigned)(unsigned short)f2bf(v1[3]) << 16);
  ((u32x4*)o)[i] = (u32x4){r0, r1, r2, r3};
}

// Pack combined weights into MFMA B-fragment-linear layout.
__global__ __launch_bounds__(256) void prep_w_k(const float* __restrict__ Ws1,
                                                const float* __restrict__ Wn1,
                                                const float* __restrict__ Ws2,
                                                const float* __restrict__ Wn2,
                                                short* __restrict__ WTp) {
  int tid = blockIdx.x * 256 + threadIdx.x;  // 0..98303
  int lane = tid & 63;
  int n0 = (tid >> 6) & 7;
  int idx3 = tid >> 9;
  int k0 = idx3 % 12;
  int lt = idx3 / 12;
  int l = lt >> 1, t = lt & 1;
  const float* Wself  = l ? Ws2 : Ws1;
  const float* Wneigh = l ? Wn2 : Wn1;
  int rA = t ? 0 : 1, rB = t ? 3 : 2;
  int n = n0 * 16 + (lane & 15);
  int kbase = k0 * 32 + (lane >> 4) * 8;
  short out[8];
#pragma unroll
  for (int j = 0; j < 8; ++j) {
    int k = kbase + j;
    int kk = k & 127, blk = k >> 7;
    float v;
    if (blk == 0)      v = Wself[rA * 16384 + kk * 128 + n] + Wself[rB * 16384 + kk * 128 + n];
    else if (blk == 1) v = Wneigh[rA * 16384 + kk * 128 + n];
    else               v = Wneigh[rB * 16384 + kk * 128 + n];
    out[j] = f2bf(v);
  }
  s16x4* dst = (s16x4*)&WTp[tid * 8];
  dst[0] = *(s16x4*)&out[0];
  dst[1] = *(s16x4*)&out[4];
}

__global__ __launch_bounds__(256) void prep_b_k(const float* __restrict__ b1,
                                                const float* __restrict__ b2,
                                                float* __restrict__ biasc) {
  int tid = blockIdx.x * 256 + threadIdx.x;
  if (tid >= 512) return;
  int l = tid >> 8, t = (tid >> 7) & 1, c = tid & 127;
  const float* b = l ? b2 : b1;
  int rA = t ? 0 : 1, rB = t ? 3 : 2;
  biasc[tid] = b[rA * 128 + c] + b[rB * 128 + c];
}

// One wave per (node, relation). Lane loads u32x4 (16B); 16 lanes cover a
// 256B row -> 4 edge rows per load instruction, 8 rows in flight per iter.
// Cross-row-group reduce via shfl_xor(16) + shfl_xor(32).
__global__ __launch_bounds__(256) void gather_mean_k(const unsigned* __restrict__ src,
    const int* __restrict__ csrA, const int* __restrict__ offA,
    const int* __restrict__ csrB, const int* __restrict__ offB,
    unsigned* __restrict__ meanA, unsigned* __restrict__ meanB) {
  int wv = __builtin_amdgcn_readfirstlane(threadIdx.x >> 6);
  int wid = blockIdx.x * 4 + wv;
  int lane = threadIdx.x & 63;
  int n = wid >> 1, rel = wid & 1;
  if (n >= N_NODES) return;
  const int* csr = rel ? csrB : csrA;
  const int* off = rel ? offB : offA;
  unsigned* mean = rel ? meanB : meanA;
  int p0 = off[n], p1 = off[n + 1];
  int deg = p1 - p0;
  int rowg = lane >> 4;          // 0..3: row within each quad
  int colg = lane & 15;          // 16B slice: u32s colg*4 .. colg*4+3
  float a[8] = {};
  for (int p = p0; p < p1; p += 8) {
    int pc0 = p + rowg, pc1 = p + 4 + rowg;
    int i0 = csr[pc0 < p1 ? pc0 : p0];
    int i1 = csr[pc1 < p1 ? pc1 : p0];
    u32x4 u0 = *(const u32x4*)(src + (size_t)i0 * 64 + colg * 4);
    u32x4 u1 = *(const u32x4*)(src + (size_t)i1 * 64 + colg * 4);
    if (pc0 < p1) {
#pragma unroll
      for (int q = 0; q < 4; ++q) {
        union { unsigned w; float f; } lo, hi;
        lo.w = u0[q] << 16; hi.w = u0[q] & 0xffff0000u;
        a[2 * q] += lo.f; a[2 * q + 1] += hi.f;
      }
    }
    if (pc1 < p1) {
#pragma unroll
      for (int q = 0; q < 4; ++q) {
        union { unsigned w; float f; } lo, hi;
        lo.w = u1[q] << 16; hi.w = u1[q] & 0xffff0000u;
        a[2 * q] += lo.f; a[2 * q + 1] += hi.f;
      }
    }
  }
#pragma unroll
  for (int q = 0; q < 8; ++q) {
    a[q] += __shfl_xor(a[q], 16);
    a[q] += __shfl_xor(a[q], 32);
  }
  if (rowg == 0) {
    float inv = 1.0f / (float)(deg > 1 ? deg : 1);
    u32x4 wv4;
#pragma unroll
    for (int q = 0; q < 4; ++q) {
      wv4[q] = (unsigned)(unsigned short)f2bf(a[2 * q] * inv) |
               ((unsigned)(unsigned short)f2bf(a[2 * q + 1] * inv) << 16);
    }
    *(u32x4*)(mean + (size_t)n * 64 + colg * 4) = wv4;
  }
}

// C[M=100000 x 128] = [self | meanA | meanB] (K=384, all bf16) @ W (in LDS)
template<int OUT_RELU_BF16>
__global__ __launch_bounds__(256) void gemm_k(const short* __restrict__ selfp,
    const short* __restrict__ meanA, const short* __restrict__ meanB,
    const short* __restrict__ WTp, const float* __restrict__ biasc,
    void* __restrict__ outp) {
  __shared__ short Wlds[6 * 8 * 512];   // 48KB
  int tid = threadIdx.x;
  int lane = tid & 63, wave = tid >> 6;
  int rowbase = blockIdx.x * 128 + wave * 32;
  int r0 = rowbase + (lane & 15), r1 = r0 + 16;
  int rc0 = r0 < N_NODES ? r0 : N_NODES - 1;
  int rc1 = r1 < N_NODES ? r1 : N_NODES - 1;
  int kg = lane >> 4;
  f32x4 acc[2][8] = {};
  for (int half = 0; half < 2; ++half) {
    __syncthreads();
    const f32x4* s = (const f32x4*)WTp + half * 3072;
    f32x4* dst = (f32x4*)Wlds;
#pragma unroll
    for (int i = 0; i < 12; ++i) dst[tid + i * 256] = s[tid + i * 256];
    __syncthreads();
    for (int k0h = 0; k0h < 6; ++k0h) {
      int k0 = half * 6 + k0h;
      int kin = (k0 & 3) * 32 + kg * 8;
      const short* mp = (k0 < 4) ? selfp : ((k0 < 8) ? meanA : meanB);
      bf16x8 a0 = *(const bf16x8*)(mp + (size_t)rc0 * 128 + kin);
      bf16x8 a1 = *(const bf16x8*)(mp + (size_t)rc1 * 128 + kin);
      const short* wb = &Wlds[k0h * 4096 + lane * 8];
#pragma unroll
      for (int n0 = 0; n0 < 8; ++n0) {
        bf16x8 b = *(const bf16x8*)(wb + n0 * 512);
        acc[0][n0] = __builtin_amdgcn_mfma_f32_16x16x32_bf16(a0, b, acc[0][n0], 0, 0, 0);
        acc[1][n0] = __builtin_amdgcn_mfma_f32_16x16x32_bf16(a1, b, acc[1][n0], 0, 0, 0);
      }
    }
  }
  int colb = lane & 15, rloc = kg * 4;
#pragma unroll
  for (int mt = 0; mt < 2; ++mt) {
    int rb = rowbase + mt * 16 + rloc;
#pragma unroll
    for (int n0 = 0; n0 < 8; ++n0) {
      int cc = n0 * 16 + colb;
      float bv = biasc[cc];
#pragma unroll
      for (int j = 0; j < 4; ++j) {
        int rr = rb + j;
        if (rr < N_NODES) {
          float v = acc[mt][n0][j] + bv;
          if (OUT_RELU_BF16) {
            ((short*)outp)[(size_t)rr * 128 + cc] = f2bf(v > 0.f ? v : 0.f);
          } else {
            ((float*)outp)[(size_t)rr * 128 + cc] = v;
          }
        }
      }
    }
  }
}

extern "C" void kernel_launch(void* const* d_in, const int* in_sizes, int n_in,
                              void* d_out, int out_size, void* d_ws, size_t ws_size,
                              hipStream_t stream) {
  (void)in_sizes; (void)n_in; (void)out_size; (void)ws_size;
  const float* xq  = (const float*)d_in[0];
  const float* xp  = (const float*)d_in[1];
  const int*   src = (const int*)d_in[2];
  const int*   dst = (const int*)d_in[3];
  const float* Ws1 = (const float*)d_in[4];
  const float* Wn1 = (const float*)d_in[5];
  const float* b1  = (const float*)d_in[6];
  const float* Ws2 = (const float*)d_in[7];
  const float* Wn2 = (const float*)d_in[8];
  const float* b2  = (const float*)d_in[9];

  char* w = (char*)d_ws;
  int*   cnt    = (int*)w;      w += (size_t)4 * N_NODES * 4;
  int*   cursor = (int*)w;      w += (size_t)4 * N_NODES * 4;
  int*   bincnt = (int*)w;      w += 512;
  int*   off    = (int*)w;      w += (size_t)4 * (N_NODES + 1) * 4;
  int*   csr    = (int*)w;      w += (size_t)4 * NEDGE * 4;
  short* meanA  = (short*)w;    w += (size_t)N_NODES * 128 * 2;
  short* meanB  = (short*)w;    w += (size_t)N_NODES * 128 * 2;
  short* h1q    = (short*)w;    w += (size_t)N_NODES * 128 * 2;
  short* h1p    = (short*)w;    w += (size_t)N_NODES * 128 * 2;
  short* xqb    = (short*)w;    w += (size_t)N_NODES * 128 * 2;
  short* xpb    = (short*)w;    w += (size_t)N_NODES * 128 * 2;
  short* WTp    = (short*)w;    w += (size_t)4 * 49152 * 2;
  float* biasc  = (float*)w;    w += 512 * 4;
  int*   bsum   = (int*)w;      w += 4 * 128 * 4;
  // staging is only live during CSR build, before meanA is first written:
  int2v* stage  = (int2v*)meanA;   // 4*8*81920*8B = 21.0MB <= 25.6MB

  dim3 b256(256);
  const int bgrid = (NEDGE + 2047) / 2048;        // 293
  const int ggrid = (N_NODES + 127) / 128;        // 782
  const int wgrid = (2 * N_NODES + 3) / 4;        // 50000 (wave per node,rel)
  const int cgrid = (N_NODES * 16 + 255) / 256;   // 6250
  const int NP1 = N_NODES + 1;

  // --- CSR build via staged binning (dst_idx fixed -> reused by both layers)
  hipMemsetAsync(cnt, 0, (size_t)8 * N_NODES * 4 + 512, stream); // cnt+cursor+bincnt
  bin_k<<<dim3(bgrid, 4), b256, 0, stream>>>(src, dst, bincnt, stage);
  count2_k<<<dim3(8 * BINK, 4), b256, 0, stream>>>(stage, bincnt, cnt);
  scan1_k<<<dim3(NBLK, 4), b256, 0, stream>>>(cnt, bsum);
  scan2_k<<<dim3(1), dim3(128), 0, stream>>>(bsum);
  scan3_k<<<dim3(NBLK, 4), b256, 0, stream>>>(cnt, bsum, off);
  fill2_k<<<dim3(8 * BINK, 4), b256, 0, stream>>>(stage, bincnt, off, cursor, csr);
  prep_w_k<<<dim3(384), b256, 0, stream>>>(Ws1, Wn1, Ws2, Wn2, WTp);
  prep_b_k<<<dim3(2), b256, 0, stream>>>(b1, b2, biasc);
  cvt_bf16_k<<<dim3(cgrid), b256, 0, stream>>>(xq, (unsigned*)xqb);
  cvt_bf16_k<<<dim3(cgrid), b256, 0, stream>>>(xp, (unsigned*)xpb);

  // ---- Layer 1, type 0 (Query): rels 1,2 ; src nodes = x_product (bf16)
  gather_mean_k<<<wgrid, b256, 0, stream>>>((const unsigned*)xpb,
      csr + 1 * NEDGE, off + 1 * NP1, csr + 2 * NEDGE, off + 2 * NP1,
      (unsigned*)meanA, (unsigned*)meanB);
  gemm_k<1><<<ggrid, b256, 0, stream>>>(xqb, meanA, meanB,
      WTp + 0 * 49152, biasc + 0, h1q);

  // ---- Layer 1, type 1 (Product): rels 0,3 ; src = x_query (bf16)
  gather_mean_k<<<wgrid, b256, 0, stream>>>((const unsigned*)xqb,
      csr + 0 * NEDGE, off + 0 * NP1, csr + 3 * NEDGE, off + 3 * NP1,
      (unsigned*)meanA, (unsigned*)meanB);
  gemm_k<1><<<ggrid, b256, 0, stream>>>(xpb, meanA, meanB,
      WTp + 1 * 49152, biasc + 128, h1p);

  // ---- Layer 2, type 0 (Query): rels 1,2 ; src = h1p (bf16)
  gather_mean_k<<<wgrid, b256, 0, stream>>>((const unsigned*)h1p,
      csr + 1 * NEDGE, off + 1 * NP1, csr + 2 * NEDGE, off + 2 * NP1,
      (unsigned*)meanA, (unsigned*)meanB);
  gemm_k<0><<<ggrid, b256, 0, stream>>>(h1q, meanA, meanB,
      WTp + 2 * 49152, biasc + 256, (float*)d_out);

  // ---- Layer 2, type 1 (Product): rels 0,3 ; src = h1q (bf16)
  gather_mean_k<<<wgrid, b256, 0, stream>>>((const unsigned*)h1q,
      csr + 0 * NEDGE, off + 0 * NP1, csr + 3 * NEDGE, off + 3 * NP1,
      (unsigned*)meanA, (unsigned*)meanB);
  gemm_k<0><<<ggrid, b256, 0, stream>>>(h1p, meanA, meanB,
      WTp + 3 * 49152, biasc + 384, (float*)d_out + (size_t)N_NODES * 128);
}

// Round 8
// 543.973 us; speedup vs baseline: 1.2810x; 1.2810x over previous
//
#include <hip/hip_runtime.h>
#include <hip/hip_bf16.h>

#define N_NODES 100000
#define NEDGE   600000
#define SCAN_B  1024
#define NBLK    98            // ceil(N_NODES / SCAN_B)
#define BSHIFT  9             // bucket = dst >> 9 (512 nodes/bucket)
#define NBUCK   196           // ceil(N_NODES / 512)
#define BCAP    3456          // per (rel,bucket) staging cap (mean 3061 + 7 sigma)

typedef __attribute__((ext_vector_type(8))) short bf16x8;
typedef __attribute__((ext_vector_type(4))) short s16x4;
typedef __attribute__((ext_vector_type(4))) float f32x4;
typedef __attribute__((ext_vector_type(4))) unsigned u32x4;
typedef __attribute__((ext_vector_type(2))) int int2v;

__device__ __forceinline__ short f2bf(float f) {
  union { float f; unsigned u; } x; x.f = f;
  unsigned r = x.u + 0x7FFFu + ((x.u >> 16) & 1u);
  return (short)(r >> 16);
}

// Phase A: bin edges into 196 per-bucket segments of (src,dst) pairs.
// Per-edge atomics are LDS-only; global atomics are per-(block,bucket)
// reservations (~196/block), NOT per-edge.
__global__ __launch_bounds__(256) void bin_k(const int* __restrict__ sidx,
                                             const int* __restrict__ didx,
                                             int* __restrict__ bincnt,
                                             int2v* __restrict__ stage) {
  __shared__ int hist[NBUCK];
  __shared__ int base[NBUCK];
  int r = blockIdx.y, t = threadIdx.x;
  int e0 = blockIdx.x * 2048 + t;
  const int* dd = didx + (size_t)r * NEDGE;
  const int* ss = sidx + (size_t)r * NEDGE;
  for (int i = t; i < NBUCK; i += 256) hist[i] = 0;
  __syncthreads();
  int sv[8], dv[8], bu[8], lr[8];
#pragma unroll
  for (int j = 0; j < 8; ++j) {
    int e = e0 + j * 256;
    if (e < NEDGE) {
      dv[j] = dd[e]; sv[j] = ss[e];
      bu[j] = dv[j] >> BSHIFT;
      lr[j] = atomicAdd(&hist[bu[j]], 1);     // LDS atomic
    }
  }
  __syncthreads();
  for (int i = t; i < NBUCK; i += 256)
    base[i] = atomicAdd(&bincnt[r * NBUCK + i], hist[i]);
  __syncthreads();
#pragma unroll
  for (int j = 0; j < 8; ++j) {
    int e = e0 + j * 256;
    if (e < NEDGE)
      stage[(size_t)(r * NBUCK + bu[j]) * BCAP + base[bu[j]] + lr[j]] =
          (int2v){sv[j], dv[j]};
  }
}

// Phase B: one block per (bucket, rel): LDS histogram of 512 dst nodes,
// coalesced cnt write. No global atomics.
__global__ __launch_bounds__(256) void hist_k(const int2v* __restrict__ stage,
                                              const int* __restrict__ bincnt,
                                              int* __restrict__ cnt) {
  __shared__ int h[512];
  int bu = blockIdx.x, r = blockIdx.y, t = threadIdx.x;
  int len = bincnt[r * NBUCK + bu];
  const int2v* sg = stage + (size_t)(r * NBUCK + bu) * BCAP;
  h[t] = 0; h[t + 256] = 0;
  __syncthreads();
  int lo = bu << BSHIFT;
  for (int i = t; i < len; i += 256) atomicAdd(&h[sg[i].y - lo], 1);  // LDS
  __syncthreads();
  int d0 = lo + t;
  if (d0 < N_NODES)       cnt[r * N_NODES + d0]       = h[t];
  if (d0 + 256 < N_NODES) cnt[r * N_NODES + d0 + 256] = h[t + 256];
}

// Phase 1: per-block chunk sums. grid (NBLK, 4), 256 thr, 4 elems/thr.
__global__ __launch_bounds__(256) void scan1_k(const int* __restrict__ cnt,
                                               int* __restrict__ bsum) {
  __shared__ int lds[256];
  int b = blockIdx.x, r = blockIdx.y, t = threadIdx.x;
  int i0 = b * SCAN_B + t * 4;
  int s = 0;
#pragma unroll
  for (int j = 0; j < 4; ++j)
    if (i0 + j < N_NODES) s += cnt[r * N_NODES + i0 + j];
  lds[t] = s;
  __syncthreads();
  for (int st = 128; st > 0; st >>= 1) {
    if (t < st) lds[t] += lds[t + st];
    __syncthreads();
  }
  if (t == 0) bsum[r * NBLK + b] = lds[0];
}

// Phase 2: exclusive scan of the NBLK block sums per relation. 1 block, 128 thr.
__global__ __launch_bounds__(128) void scan2_k(int* __restrict__ bsum) {
  __shared__ int buf[128];
  int t = threadIdx.x;
  for (int r = 0; r < 4; ++r) {
    int v = (t < NBLK) ? bsum[r * NBLK + t] : 0;
    buf[t] = v;
    __syncthreads();
    for (int st = 1; st < 128; st <<= 1) {
      int x = (t >= st) ? buf[t - st] : 0;
      __syncthreads();
      buf[t] += x;
      __syncthreads();
    }
    if (t < NBLK) bsum[r * NBLK + t] = buf[t] - v;   // exclusive
    __syncthreads();
  }
}

// Phase 3: local exclusive scan + block base -> off. grid (NBLK, 4), 256 thr.
__global__ __launch_bounds__(256) void scan3_k(const int* __restrict__ cnt,
                                               const int* __restrict__ bsum,
                                               int* __restrict__ off) {
  __shared__ int lds[256];
  int b = blockIdx.x, r = blockIdx.y, t = threadIdx.x;
  int i0 = b * SCAN_B + t * 4;
  int c[4] = {0, 0, 0, 0};
#pragma unroll
  for (int j = 0; j < 4; ++j)
    if (i0 + j < N_NODES) c[j] = cnt[r * N_NODES + i0 + j];
  int s = c[0] + c[1] + c[2] + c[3];
  lds[t] = s;
  __syncthreads();
  for (int st = 1; st < 256; st <<= 1) {
    int x = (t >= st) ? lds[t - st] : 0;
    __syncthreads();
    lds[t] += x;
    __syncthreads();
  }
  int run = bsum[r * NBLK + b] + lds[t] - s;
  int* o = off + r * (N_NODES + 1);
#pragma unroll
  for (int j = 0; j < 4; ++j) {
    if (i0 + j < N_NODES) { o[i0 + j] = run; run += c[j]; }
  }
  if (b == 0 && t == 0) o[N_NODES] = NEDGE;
}

// Phase C: one block per (bucket, rel): place edges with LDS-only cursors.
// csr region per block is private & contiguous (~12KB) -> single-L2 writes,
// lines fill before eviction. Zero global atomics.
__global__ __launch_bounds__(256) void place_k(const int2v* __restrict__ stage,
                                               const int* __restrict__ bincnt,
                                               const int* __restrict__ off,
                                               int* __restrict__ csr) {
  __shared__ int ofl[512];
  __shared__ int cur[512];
  int bu = blockIdx.x, r = blockIdx.y, t = threadIdx.x;
  int len = bincnt[r * NBUCK + bu];
  const int2v* sg = stage + (size_t)(r * NBUCK + bu) * BCAP;
  const int* of = off + r * (N_NODES + 1);
  int* cs = csr + (size_t)r * NEDGE;
  int lo = bu << BSHIFT;
  int d0 = lo + t;
  ofl[t]       = (d0 < N_NODES) ? of[d0] : 0;
  ofl[t + 256] = (d0 + 256 < N_NODES) ? of[d0 + 256] : 0;
  cur[t] = 0; cur[t + 256] = 0;
  __syncthreads();
  for (int i = t; i < len; i += 256) {
    int2v sd = sg[i];
    int dl = sd.y - lo;
    int pos = ofl[dl] + atomicAdd(&cur[dl], 1);   // LDS atomic
    cs[pos] = sd.x;
  }
}

// f32 -> packed bf16 (2 per u32); each thread converts 8 floats.
__global__ __launch_bounds__(256) void cvt_bf16_k(const float* __restrict__ x,
                                                  unsigned* __restrict__ o) {
  int i = blockIdx.x * 256 + threadIdx.x;     // i < N_NODES*16
  if (i >= N_NODES * 16) return;
  f32x4 v0 = ((const f32x4*)x)[i * 2];
  f32x4 v1 = ((const f32x4*)x)[i * 2 + 1];
  unsigned r0 = (unsigned)(unsigned short)f2bf(v0[0]) |
                ((unsigned)(unsigned short)f2bf(v0[1]) << 16);
  unsigned r1 = (unsigned)(unsigned short)f2bf(v0[2]) |
                ((unsigned)(unsigned short)f2bf(v0[3]) << 16);
  unsigned r2 = (unsigned)(unsigned short)f2bf(v1[0]) |
                ((unsigned)(unsigned short)f2bf(v1[1]) << 16);
  unsigned r3 = (unsigned)(unsigned short)f2bf(v1[2]) |
                ((unsigned)(unsigned short)f2bf(v1[3]) << 16);
  ((u32x4*)o)[i] = (u32x4){r0, r1, r2, r3};
}

// Pack combined weights into MFMA B-fragment-linear layout.
__global__ __launch_bounds__(256) void prep_w_k(const float* __restrict__ Ws1,
                                                const float* __restrict__ Wn1,
                                                const float* __restrict__ Ws2,
                                                const float* __restrict__ Wn2,
                                                short* __restrict__ WTp) {
  int tid = blockIdx.x * 256 + threadIdx.x;  // 0..98303
  int lane = tid & 63;
  int n0 = (tid >> 6) & 7;
  int idx3 = tid >> 9;
  int k0 = idx3 % 12;
  int lt = idx3 / 12;
  int l = lt >> 1, t = lt & 1;
  const float* Wself  = l ? Ws2 : Ws1;
  const float* Wneigh = l ? Wn2 : Wn1;
  int rA = t ? 0 : 1, rB = t ? 3 : 2;
  int n = n0 * 16 + (lane & 15);
  int kbase = k0 * 32 + (lane >> 4) * 8;
  short out[8];
#pragma unroll
  for (int j = 0; j < 8; ++j) {
    int k = kbase + j;
    int kk = k & 127, blk = k >> 7;
    float v;
    if (blk == 0)      v = Wself[rA * 16384 + kk * 128 + n] + Wself[rB * 16384 + kk * 128 + n];
    else if (blk == 1) v = Wneigh[rA * 16384 + kk * 128 + n];
    else               v = Wneigh[rB * 16384 + kk * 128 + n];
    out[j] = f2bf(v);
  }
  s16x4* dst = (s16x4*)&WTp[tid * 8];
  dst[0] = *(s16x4*)&out[0];
  dst[1] = *(s16x4*)&out[4];
}

__global__ __launch_bounds__(256) void prep_b_k(const float* __restrict__ b1,
                                                const float* __restrict__ b2,
                                                float* __restrict__ biasc) {
  int tid = blockIdx.x * 256 + threadIdx.x;
  if (tid >= 512) return;
  int l = tid >> 8, t = (tid >> 7) & 1, c = tid & 127;
  const float* b = l ? b2 : b1;
  int rA = t ? 0 : 1, rB = t ? 3 : 2;
  biasc[tid] = b[rA * 128 + c] + b[rB * 128 + c];
}

// One wave per (node, relation). Lane loads u32x4 (16B); 16 lanes cover a
// 256B row -> 4 edge rows per load instruction, 8 rows in flight per iter.
__global__ __launch_bounds__(256) void gather_mean_k(const unsigned* __restrict__ src,
    const int* __restrict__ csrA, const int* __restrict__ offA,
    const int* __restrict__ csrB, const int* __restrict__ offB,
    unsigned* __restrict__ meanA, unsigned* __restrict__ meanB) {
  int wv = __builtin_amdgcn_readfirstlane(threadIdx.x >> 6);
  int wid = blockIdx.x * 4 + wv;
  int lane = threadIdx.x & 63;
  int n = wid >> 1, rel = wid & 1;
  if (n >= N_NODES) return;
  const int* csr = rel ? csrB : csrA;
  const int* off = rel ? offB : offA;
  unsigned* mean = rel ? meanB : meanA;
  int p0 = off[n], p1 = off[n + 1];
  int deg = p1 - p0;
  int rowg = lane >> 4;          // 0..3: row within each quad
  int colg = lane & 15;          // 16B slice: u32s colg*4 .. colg*4+3
  float a[8] = {};
  for (int p = p0; p < p1; p += 8) {
    int pc0 = p + rowg, pc1 = p + 4 + rowg;
    int i0 = csr[pc0 < p1 ? pc0 : p0];
    int i1 = csr[pc1 < p1 ? pc1 : p0];
    u32x4 u0 = *(const u32x4*)(src + (size_t)i0 * 64 + colg * 4);
    u32x4 u1 = *(const u32x4*)(src + (size_t)i1 * 64 + colg * 4);
    if (pc0 < p1) {
#pragma unroll
      for (int q = 0; q < 4; ++q) {
        union { unsigned w; float f; } lo, hi;
        lo.w = u0[q] << 16; hi.w = u0[q] & 0xffff0000u;
        a[2 * q] += lo.f; a[2 * q + 1] += hi.f;
      }
    }
    if (pc1 < p1) {
#pragma unroll
      for (int q = 0; q < 4; ++q) {
        union { unsigned w; float f; } lo, hi;
        lo.w = u1[q] << 16; hi.w = u1[q] & 0xffff0000u;
        a[2 * q] += lo.f; a[2 * q + 1] += hi.f;
      }
    }
  }
#pragma unroll
  for (int q = 0; q < 8; ++q) {
    a[q] += __shfl_xor(a[q], 16);
    a[q] += __shfl_xor(a[q], 32);
  }
  if (rowg == 0) {
    float inv = 1.0f / (float)(deg > 1 ? deg : 1);
    u32x4 wv4;
#pragma unroll
    for (int q = 0; q < 4; ++q) {
      wv4[q] = (unsigned)(unsigned short)f2bf(a[2 * q] * inv) |
               ((unsigned)(unsigned short)f2bf(a[2 * q + 1] * inv) << 16);
    }
    *(u32x4*)(mean + (size_t)n * 64 + colg * 4) = wv4;
  }
}

// C[M=100000 x 128] = [self | meanA | meanB] (K=384, all bf16) @ W (in LDS)
template<int OUT_RELU_BF16>
__global__ __launch_bounds__(256) void gemm_k(const short* __restrict__ selfp,
    const short* __restrict__ meanA, const short* __restrict__ meanB,
    const short* __restrict__ WTp, const float* __restrict__ biasc,
    void* __restrict__ outp) {
  __shared__ short Wlds[6 * 8 * 512];   // 48KB
  int tid = threadIdx.x;
  int lane = tid & 63, wave = tid >> 6;
  int rowbase = blockIdx.x * 128 + wave * 32;
  int r0 = rowbase + (lane & 15), r1 = r0 + 16;
  int rc0 = r0 < N_NODES ? r0 : N_NODES - 1;
  int rc1 = r1 < N_NODES ? r1 : N_NODES - 1;
  int kg = lane >> 4;
  f32x4 acc[2][8] = {};
  for (int half = 0; half < 2; ++half) {
    __syncthreads();
    const f32x4* s = (const f32x4*)WTp + half * 3072;
    f32x4* dst = (f32x4*)Wlds;
#pragma unroll
    for (int i = 0; i < 12; ++i) dst[tid + i * 256] = s[tid + i * 256];
    __syncthreads();
    for (int k0h = 0; k0h < 6; ++k0h) {
      int k0 = half * 6 + k0h;
      int kin = (k0 & 3) * 32 + kg * 8;
      const short* mp = (k0 < 4) ? selfp : ((k0 < 8) ? meanA : meanB);
      bf16x8 a0 = *(const bf16x8*)(mp + (size_t)rc0 * 128 + kin);
      bf16x8 a1 = *(const bf16x8*)(mp + (size_t)rc1 * 128 + kin);
      const short* wb = &Wlds[k0h * 4096 + lane * 8];
#pragma unroll
      for (int n0 = 0; n0 < 8; ++n0) {
        bf16x8 b = *(const bf16x8*)(wb + n0 * 512);
        acc[0][n0] = __builtin_amdgcn_mfma_f32_16x16x32_bf16(a0, b, acc[0][n0], 0, 0, 0);
        acc[1][n0] = __builtin_amdgcn_mfma_f32_16x16x32_bf16(a1, b, acc[1][n0], 0, 0, 0);
      }
    }
  }
  int colb = lane & 15, rloc = kg * 4;
#pragma unroll
  for (int mt = 0; mt < 2; ++mt) {
    int rb = rowbase + mt * 16 + rloc;
#pragma unroll
    for (int n0 = 0; n0 < 8; ++n0) {
      int cc = n0 * 16 + colb;
      float bv = biasc[cc];
#pragma unroll
      for (int j = 0; j < 4; ++j) {
        int rr = rb + j;
        if (rr < N_NODES) {
          float v = acc[mt][n0][j] + bv;
          if (OUT_RELU_BF16) {
            ((short*)outp)[(size_t)rr * 128 + cc] = f2bf(v > 0.f ? v : 0.f);
          } else {
            ((float*)outp)[(size_t)rr * 128 + cc] = v;
          }
        }
      }
    }
  }
}

extern "C" void kernel_launch(void* const* d_in, const int* in_sizes, int n_in,
                              void* d_out, int out_size, void* d_ws, size_t ws_size,
                              hipStream_t stream) {
  (void)in_sizes; (void)n_in; (void)out_size; (void)ws_size;
  const float* xq  = (const float*)d_in[0];
  const float* xp  = (const float*)d_in[1];
  const int*   src = (const int*)d_in[2];
  const int*   dst = (const int*)d_in[3];
  const float* Ws1 = (const float*)d_in[4];
  const float* Wn1 = (const float*)d_in[5];
  const float* b1  = (const float*)d_in[6];
  const float* Ws2 = (const float*)d_in[7];
  const float* Wn2 = (const float*)d_in[8];
  const float* b2  = (const float*)d_in[9];

  char* w = (char*)d_ws;
  int*   cnt    = (int*)w;      w += (size_t)4 * N_NODES * 4;
  int*   bincnt = (int*)w;      w += 4096;
  int*   off    = (int*)w;      w += (size_t)4 * (N_NODES + 1) * 4;
  int*   csr    = (int*)w;      w += (size_t)4 * NEDGE * 4;
  short* meanA  = (short*)w;    w += (size_t)N_NODES * 128 * 2;
  short* meanB  = (short*)w;    w += (size_t)N_NODES * 128 * 2;
  short* h1q    = (short*)w;    w += (size_t)N_NODES * 128 * 2;
  short* h1p    = (short*)w;    w += (size_t)N_NODES * 128 * 2;
  short* xqb    = (short*)w;    w += (size_t)N_NODES * 128 * 2;
  short* xpb    = (short*)w;    w += (size_t)N_NODES * 128 * 2;
  short* WTp    = (short*)w;    w += (size_t)4 * 49152 * 2;
  float* biasc  = (float*)w;    w += 512 * 4;
  int*   bsum   = (int*)w;      w += 4 * 128 * 4;
  // staging is only live during CSR build, before meanA is first written:
  int2v* stage  = (int2v*)meanA;   // 4*196*3456*8B = 21.7MB <= 25.6MB

  dim3 b256(256);
  const int bgrid = (NEDGE + 2047) / 2048;        // 293
  const int ggrid = (N_NODES + 127) / 128;        // 782
  const int wgrid = (2 * N_NODES + 3) / 4;        // 50000 (wave per node,rel)
  const int cgrid = (N_NODES * 16 + 255) / 256;   // 6250
  const int NP1 = N_NODES + 1;

  // --- CSR build via bucket counting-sort (no per-edge global atomics)
  hipMemsetAsync(bincnt, 0, 4096, stream);
  bin_k<<<dim3(bgrid, 4), b256, 0, stream>>>(src, dst, bincnt, stage);
  hist_k<<<dim3(NBUCK, 4), b256, 0, stream>>>(stage, bincnt, cnt);
  scan1_k<<<dim3(NBLK, 4), b256, 0, stream>>>(cnt, bsum);
  scan2_k<<<dim3(1), dim3(128), 0, stream>>>(bsum);
  scan3_k<<<dim3(NBLK, 4), b256, 0, stream>>>(cnt, bsum, off);
  place_k<<<dim3(NBUCK, 4), b256, 0, stream>>>(stage, bincnt, off, csr);
  prep_w_k<<<dim3(384), b256, 0, stream>>>(Ws1, Wn1, Ws2, Wn2, WTp);
  prep_b_k<<<dim3(2), b256, 0, stream>>>(b1, b2, biasc);
  cvt_bf16_k<<<dim3(cgrid), b256, 0, stream>>>(xq, (unsigned*)xqb);
  cvt_bf16_k<<<dim3(cgrid), b256, 0, stream>>>(xp, (unsigned*)xpb);

  // ---- Layer 1, type 0 (Query): rels 1,2 ; src nodes = x_product (bf16)
  gather_mean_k<<<wgrid, b256, 0, stream>>>((const unsigned*)xpb,
      csr + 1 * NEDGE, off + 1 * NP1, csr + 2 * NEDGE, off + 2 * NP1,
      (unsigned*)meanA, (unsigned*)meanB);
  gemm_k<1><<<ggrid, b256, 0, stream>>>(xqb, meanA, meanB,
      WTp + 0 * 49152, biasc + 0, h1q);

  // ---- Layer 1, type 1 (Product): rels 0,3 ; src = x_query (bf16)
  gather_mean_k<<<wgrid, b256, 0, stream>>>((const unsigned*)xqb,
      csr + 0 * NEDGE, off + 0 * NP1, csr + 3 * NEDGE, off + 3 * NP1,
      (unsigned*)meanA, (unsigned*)meanB);
  gemm_k<1><<<ggrid, b256, 0, stream>>>(xpb, meanA, meanB,
      WTp + 1 * 49152, biasc + 128, h1p);

  // ---- Layer 2, type 0 (Query): rels 1,2 ; src = h1p (bf16)
  gather_mean_k<<<wgrid, b256, 0, stream>>>((const unsigned*)h1p,
      csr + 1 * NEDGE, off + 1 * NP1, csr + 2 * NEDGE, off + 2 * NP1,
      (unsigned*)meanA, (unsigned*)meanB);
  gemm_k<0><<<ggrid, b256, 0, stream>>>(h1q, meanA, meanB,
      WTp + 2 * 49152, biasc + 256, (float*)d_out);

  // ---- Layer 2, type 1 (Product): rels 0,3 ; src = h1q (bf16)
  gather_mean_k<<<wgrid, b256, 0, stream>>>((const unsigned*)h1q,
      csr + 0 * NEDGE, off + 0 * NP1, csr + 3 * NEDGE, off + 3 * NP1,
      (unsigned*)meanA, (unsigned*)meanB);
  gemm_k<0><<<ggrid, b256, 0, stream>>>(h1p, meanA, meanB,
      WTp + 3 * 49152, biasc + 384, (float*)d_out + (size_t)N_NODES * 128);
}

// Round 9
// 471.890 us; speedup vs baseline: 1.4766x; 1.1528x over previous
//
#include <hip/hip_runtime.h>
#include <hip/hip_bf16.h>

#define N_NODES 100000
#define NEDGE   600000
#define SCAN_B  1024
#define NBLK    98            // ceil(N_NODES / SCAN_B)
#define BSHIFT  9             // bucket = dst >> 9 (512 nodes/bucket)
#define NBUCK   196           // ceil(N_NODES / 512)
#define BCAP    3456          // per (rel,bucket) staging cap (mean 3061 + 7 sigma)

typedef __attribute__((ext_vector_type(8))) short bf16x8;
typedef __attribute__((ext_vector_type(4))) short s16x4;
typedef __attribute__((ext_vector_type(4))) float f32x4;
typedef __attribute__((ext_vector_type(4))) unsigned u32x4;
typedef __attribute__((ext_vector_type(2))) int int2v;

__device__ __forceinline__ short f2bf(float f) {
  union { float f; unsigned u; } x; x.f = f;
  unsigned r = x.u + 0x7FFFu + ((x.u >> 16) & 1u);
  return (short)(r >> 16);
}

// Phase A: bin edges into 196 per-bucket segments of (src,dst) pairs.
__global__ __launch_bounds__(256) void bin_k(const int* __restrict__ sidx,
                                             const int* __restrict__ didx,
                                             int* __restrict__ bincnt,
                                             int2v* __restrict__ stage) {
  __shared__ int hist[NBUCK];
  __shared__ int base[NBUCK];
  int r = blockIdx.y, t = threadIdx.x;
  int e0 = blockIdx.x * 2048 + t;
  const int* dd = didx + (size_t)r * NEDGE;
  const int* ss = sidx + (size_t)r * NEDGE;
  for (int i = t; i < NBUCK; i += 256) hist[i] = 0;
  __syncthreads();
  int sv[8], dv[8], bu[8], lr[8];
#pragma unroll
  for (int j = 0; j < 8; ++j) {
    int e = e0 + j * 256;
    if (e < NEDGE) {
      dv[j] = dd[e]; sv[j] = ss[e];
      bu[j] = dv[j] >> BSHIFT;
      lr[j] = atomicAdd(&hist[bu[j]], 1);     // LDS atomic
    }
  }
  __syncthreads();
  for (int i = t; i < NBUCK; i += 256)
    base[i] = atomicAdd(&bincnt[r * NBUCK + i], hist[i]);
  __syncthreads();
#pragma unroll
  for (int j = 0; j < 8; ++j) {
    int e = e0 + j * 256;
    if (e < NEDGE)
      stage[(size_t)(r * NBUCK + bu[j]) * BCAP + base[bu[j]] + lr[j]] =
          (int2v){sv[j], dv[j]};
  }
}

// Phase B: one block per (bucket, rel): LDS histogram, coalesced cnt write.
__global__ __launch_bounds__(256) void hist_k(const int2v* __restrict__ stage,
                                              const int* __restrict__ bincnt,
                                              int* __restrict__ cnt) {
  __shared__ int h[512];
  int bu = blockIdx.x, r = blockIdx.y, t = threadIdx.x;
  int len = bincnt[r * NBUCK + bu];
  const int2v* sg = stage + (size_t)(r * NBUCK + bu) * BCAP;
  h[t] = 0; h[t + 256] = 0;
  __syncthreads();
  int lo = bu << BSHIFT;
  for (int i = t; i < len; i += 256) atomicAdd(&h[sg[i].y - lo], 1);  // LDS
  __syncthreads();
  int d0 = lo + t;
  if (d0 < N_NODES)       cnt[r * N_NODES + d0]       = h[t];
  if (d0 + 256 < N_NODES) cnt[r * N_NODES + d0 + 256] = h[t + 256];
}

__global__ __launch_bounds__(256) void scan1_k(const int* __restrict__ cnt,
                                               int* __restrict__ bsum) {
  __shared__ int lds[256];
  int b = blockIdx.x, r = blockIdx.y, t = threadIdx.x;
  int i0 = b * SCAN_B + t * 4;
  int s = 0;
#pragma unroll
  for (int j = 0; j < 4; ++j)
    if (i0 + j < N_NODES) s += cnt[r * N_NODES + i0 + j];
  lds[t] = s;
  __syncthreads();
  for (int st = 128; st > 0; st >>= 1) {
    if (t < st) lds[t] += lds[t + st];
    __syncthreads();
  }
  if (t == 0) bsum[r * NBLK + b] = lds[0];
}

__global__ __launch_bounds__(128) void scan2_k(int* __restrict__ bsum) {
  __shared__ int buf[128];
  int t = threadIdx.x;
  for (int r = 0; r < 4; ++r) {
    int v = (t < NBLK) ? bsum[r * NBLK + t] : 0;
    buf[t] = v;
    __syncthreads();
    for (int st = 1; st < 128; st <<= 1) {
      int x = (t >= st) ? buf[t - st] : 0;
      __syncthreads();
      buf[t] += x;
      __syncthreads();
    }
    if (t < NBLK) bsum[r * NBLK + t] = buf[t] - v;   // exclusive
    __syncthreads();
  }
}

__global__ __launch_bounds__(256) void scan3_k(const int* __restrict__ cnt,
                                               const int* __restrict__ bsum,
                                               int* __restrict__ off) {
  __shared__ int lds[256];
  int b = blockIdx.x, r = blockIdx.y, t = threadIdx.x;
  int i0 = b * SCAN_B + t * 4;
  int c[4] = {0, 0, 0, 0};
#pragma unroll
  for (int j = 0; j < 4; ++j)
    if (i0 + j < N_NODES) c[j] = cnt[r * N_NODES + i0 + j];
  int s = c[0] + c[1] + c[2] + c[3];
  lds[t] = s;
  __syncthreads();
  for (int st = 1; st < 256; st <<= 1) {
    int x = (t >= st) ? lds[t - st] : 0;
    __syncthreads();
    lds[t] += x;
    __syncthreads();
  }
  int run = bsum[r * NBLK + b] + lds[t] - s;
  int* o = off + r * (N_NODES + 1);
#pragma unroll
  for (int j = 0; j < 4; ++j) {
    if (i0 + j < N_NODES) { o[i0 + j] = run; run += c[j]; }
  }
  if (b == 0 && t == 0) o[N_NODES] = NEDGE;
}

// Phase C: one block per (bucket, rel): place edges with LDS-only cursors.
__global__ __launch_bounds__(256) void place_k(const int2v* __restrict__ stage,
                                               const int* __restrict__ bincnt,
                                               const int* __restrict__ off,
                                               int* __restrict__ csr) {
  __shared__ int ofl[512];
  __shared__ int cur[512];
  int bu = blockIdx.x, r = blockIdx.y, t = threadIdx.x;
  int len = bincnt[r * NBUCK + bu];
  const int2v* sg = stage + (size_t)(r * NBUCK + bu) * BCAP;
  const int* of = off + r * (N_NODES + 1);
  int* cs = csr + (size_t)r * NEDGE;
  int lo = bu << BSHIFT;
  int d0 = lo + t;
  ofl[t]       = (d0 < N_NODES) ? of[d0] : 0;
  ofl[t + 256] = (d0 + 256 < N_NODES) ? of[d0 + 256] : 0;
  cur[t] = 0; cur[t + 256] = 0;
  __syncthreads();
  for (int i = t; i < len; i += 256) {
    int2v sd = sg[i];
    int dl = sd.y - lo;
    int pos = ofl[dl] + atomicAdd(&cur[dl], 1);   // LDS atomic
    cs[pos] = sd.x;
  }
}

// f32 -> packed bf16 for both inputs in one dispatch (blockIdx.y selects).
__global__ __launch_bounds__(256) void cvt2_k(const float* __restrict__ x0,
                                              const float* __restrict__ x1,
                                              unsigned* __restrict__ o0,
                                              unsigned* __restrict__ o1) {
  const float* x = blockIdx.y ? x1 : x0;
  unsigned* o = blockIdx.y ? o1 : o0;
  int i = blockIdx.x * 256 + threadIdx.x;     // i < N_NODES*16
  if (i >= N_NODES * 16) return;
  f32x4 v0 = ((const f32x4*)x)[i * 2];
  f32x4 v1 = ((const f32x4*)x)[i * 2 + 1];
  unsigned r0 = (unsigned)(unsigned short)f2bf(v0[0]) |
                ((unsigned)(unsigned short)f2bf(v0[1]) << 16);
  unsigned r1 = (unsigned)(unsigned short)f2bf(v0[2]) |
                ((unsigned)(unsigned short)f2bf(v0[3]) << 16);
  unsigned r2 = (unsigned)(unsigned short)f2bf(v1[0]) |
                ((unsigned)(unsigned short)f2bf(v1[1]) << 16);
  unsigned r3 = (unsigned)(unsigned short)f2bf(v1[2]) |
                ((unsigned)(unsigned short)f2bf(v1[3]) << 16);
  ((u32x4*)o)[i] = (u32x4){r0, r1, r2, r3};
}

// Pack combined weights into MFMA B-fragment-linear layout.
__global__ __launch_bounds__(256) void prep_w_k(const float* __restrict__ Ws1,
                                                const float* __restrict__ Wn1,
                                                const float* __restrict__ Ws2,
                                                const float* __restrict__ Wn2,
                                                short* __restrict__ WTp) {
  int tid = blockIdx.x * 256 + threadIdx.x;  // 0..98303
  int lane = tid & 63;
  int n0 = (tid >> 6) & 7;
  int idx3 = tid >> 9;
  int k0 = idx3 % 12;
  int lt = idx3 / 12;
  int l = lt >> 1, t = lt & 1;
  const float* Wself  = l ? Ws2 : Ws1;
  const float* Wneigh = l ? Wn2 : Wn1;
  int rA = t ? 0 : 1, rB = t ? 3 : 2;
  int n = n0 * 16 + (lane & 15);
  int kbase = k0 * 32 + (lane >> 4) * 8;
  short out[8];
#pragma unroll
  for (int j = 0; j < 8; ++j) {
    int k = kbase + j;
    int kk = k & 127, blk = k >> 7;
    float v;
    if (blk == 0)      v = Wself[rA * 16384 + kk * 128 + n] + Wself[rB * 16384 + kk * 128 + n];
    else if (blk == 1) v = Wneigh[rA * 16384 + kk * 128 + n];
    else               v = Wneigh[rB * 16384 + kk * 128 + n];
    out[j] = f2bf(v);
  }
  s16x4* dst = (s16x4*)&WTp[tid * 8];
  dst[0] = *(s16x4*)&out[0];
  dst[1] = *(s16x4*)&out[4];
}

__global__ __launch_bounds__(256) void prep_b_k(const float* __restrict__ b1,
                                                const float* __restrict__ b2,
                                                float* __restrict__ biasc) {
  int tid = blockIdx.x * 256 + threadIdx.x;
  if (tid >= 512) return;
  int l = tid >> 8, t = (tid >> 7) & 1, c = tid & 127;
  const float* b = l ? b2 : b1;
  int rA = t ? 0 : 1, rB = t ? 3 : 2;
  biasc[tid] = b[rA * 128 + c] + b[rB * 128 + c];
}

#define ACC8(u, a)                                            \
  {                                                           \
    _Pragma("unroll") for (int q = 0; q < 4; ++q) {           \
      union { unsigned w; float f; } lo_, hi_;                \
      lo_.w = (u)[q] << 16; hi_.w = (u)[q] & 0xffff0000u;     \
      (a)[2 * q] += lo_.f; (a)[2 * q + 1] += hi_.f;           \
    }                                                         \
  }

__device__ __forceinline__ int clampi(int q, int p0, int p1) {
  int t = q < p1 ? q : p0;
  return t < NEDGE ? t : 0;
}

// One wave per node handling BOTH relations (interleaved issue -> 2x the
// independent memory chains per wave). Both node types in one dispatch:
// waves [0,N) = type0, [N,2N) = type1.
__global__ __launch_bounds__(256) void gather2_k(
    const unsigned* __restrict__ src0, const unsigned* __restrict__ src1,
    const int* __restrict__ csr, const int* __restrict__ off,
    unsigned* __restrict__ m00, unsigned* __restrict__ m01,
    unsigned* __restrict__ m10, unsigned* __restrict__ m11) {
  int wv = __builtin_amdgcn_readfirstlane(threadIdx.x >> 6);
  int wid = blockIdx.x * 4 + wv;          // 0 .. 2*N_NODES-1
  int lane = threadIdx.x & 63;
  int type = wid >= N_NODES;
  int n = type ? wid - N_NODES : wid;
  const unsigned* src = type ? src1 : src0;
  const int* csrA = csr + (type ? 0 : 1) * NEDGE;
  const int* csrB = csr + (type ? 3 : 2) * NEDGE;
  const int* offA = off + (type ? 0 : 1) * (N_NODES + 1);
  const int* offB = off + (type ? 3 : 2) * (N_NODES + 1);
  unsigned* mA = type ? m10 : m00;
  unsigned* mB = type ? m11 : m01;
  int pA0 = offA[n], pA1 = offA[n + 1];
  int pB0 = offB[n], pB1 = offB[n + 1];
  int degA = pA1 - pA0, degB = pB1 - pB0;
  int rowg = lane >> 4;          // 0..3: row within each quad
  int colg = lane & 15;          // 16B slice: u32s colg*4 .. colg*4+3
  float a[8] = {}, b[8] = {};
  // fast path: first 8 edges of each relation, all loads issued up front
  {
    int ia0 = csrA[clampi(pA0 + rowg,     pA0, pA1)];
    int ia1 = csrA[clampi(pA0 + 4 + rowg, pA0, pA1)];
    int ib0 = csrB[clampi(pB0 + rowg,     pB0, pB1)];
    int ib1 = csrB[clampi(pB0 + 4 + rowg, pB0, pB1)];
    u32x4 ua0 = *(const u32x4*)(src + (size_t)ia0 * 64 + colg * 4);
    u32x4 ua1 = *(const u32x4*)(src + (size_t)ia1 * 64 + colg * 4);
    u32x4 ub0 = *(const u32x4*)(src + (size_t)ib0 * 64 + colg * 4);
    u32x4 ub1 = *(const u32x4*)(src + (size_t)ib1 * 64 + colg * 4);
    if (pA0 + rowg     < pA1) ACC8(ua0, a);
    if (pA0 + 4 + rowg < pA1) ACC8(ua1, a);
    if (pB0 + rowg     < pB1) ACC8(ub0, b);
    if (pB0 + 4 + rowg < pB1) ACC8(ub1, b);
  }
  // remainder (deg > 8, ~15% of nodes per relation)
  for (int p = pA0 + 8; p < pA1; p += 8) {
    int i0 = csrA[clampi(p + rowg,     pA0, pA1)];
    int i1 = csrA[clampi(p + 4 + rowg, pA0, pA1)];
    u32x4 u0 = *(const u32x4*)(src + (size_t)i0 * 64 + colg * 4);
    u32x4 u1 = *(const u32x4*)(src + (size_t)i1 * 64 + colg * 4);
    if (p + rowg     < pA1) ACC8(u0, a);
    if (p + 4 + rowg < pA1) ACC8(u1, a);
  }
  for (int p = pB0 + 8; p < pB1; p += 8) {
    int i0 = csrB[clampi(p + rowg,     pB0, pB1)];
    int i1 = csrB[clampi(p + 4 + rowg, pB0, pB1)];
    u32x4 u0 = *(const u32x4*)(src + (size_t)i0 * 64 + colg * 4);
    u32x4 u1 = *(const u32x4*)(src + (size_t)i1 * 64 + colg * 4);
    if (p + rowg     < pB1) ACC8(u0, b);
    if (p + 4 + rowg < pB1) ACC8(u1, b);
  }
#pragma unroll
  for (int q = 0; q < 8; ++q) {
    a[q] += __shfl_xor(a[q], 16); a[q] += __shfl_xor(a[q], 32);
    b[q] += __shfl_xor(b[q], 16); b[q] += __shfl_xor(b[q], 32);
  }
  if (rowg == 0) {
    float invA = 1.0f / (float)(degA > 1 ? degA : 1);
    float invB = 1.0f / (float)(degB > 1 ? degB : 1);
    u32x4 wa, wb;
#pragma unroll
    for (int q = 0; q < 4; ++q) {
      wa[q] = (unsigned)(unsigned short)f2bf(a[2 * q] * invA) |
              ((unsigned)(unsigned short)f2bf(a[2 * q + 1] * invA) << 16);
      wb[q] = (unsigned)(unsigned short)f2bf(b[2 * q] * invB) |
              ((unsigned)(unsigned short)f2bf(b[2 * q + 1] * invB) << 16);
    }
    *(u32x4*)(mA + (size_t)n * 64 + colg * 4) = wa;
    *(u32x4*)(mB + (size_t)n * 64 + colg * 4) = wb;
  }
}

// Both types in one dispatch (blockIdx.y). C = [self|meanA|meanB] @ W + b.
template<int OUT_RELU_BF16>
__global__ __launch_bounds__(256) void gemm2_k(
    const short* __restrict__ self0, const short* __restrict__ self1,
    const short* __restrict__ mA0, const short* __restrict__ mB0,
    const short* __restrict__ mA1, const short* __restrict__ mB1,
    const short* __restrict__ WTpL, const float* __restrict__ biascL,
    void* __restrict__ out0, void* __restrict__ out1) {
  __shared__ short Wlds[6 * 8 * 512];   // 48KB
  int type = blockIdx.y;
  const short* selfp = type ? self1 : self0;
  const short* meanA = type ? mA1 : mA0;
  const short* meanB = type ? mB1 : mB0;
  const short* WTp = WTpL + type * 49152;
  const float* biasc = biascL + type * 128;
  void* outp = type ? out1 : out0;
  int tid = threadIdx.x;
  int lane = tid & 63, wave = tid >> 6;
  int rowbase = blockIdx.x * 128 + wave * 32;
  int r0 = rowbase + (lane & 15), r1 = r0 + 16;
  int rc0 = r0 < N_NODES ? r0 : N_NODES - 1;
  int rc1 = r1 < N_NODES ? r1 : N_NODES - 1;
  int kg = lane >> 4;
  f32x4 acc[2][8] = {};
  for (int half = 0; half < 2; ++half) {
    __syncthreads();
    const f32x4* s = (const f32x4*)WTp + half * 3072;
    f32x4* dst = (f32x4*)Wlds;
#pragma unroll
    for (int i = 0; i < 12; ++i) dst[tid + i * 256] = s[tid + i * 256];
    __syncthreads();
    for (int k0h = 0; k0h < 6; ++k0h) {
      int k0 = half * 6 + k0h;
      int kin = (k0 & 3) * 32 + kg * 8;
      const short* mp = (k0 < 4) ? selfp : ((k0 < 8) ? meanA : meanB);
      bf16x8 a0 = *(const bf16x8*)(mp + (size_t)rc0 * 128 + kin);
      bf16x8 a1 = *(const bf16x8*)(mp + (size_t)rc1 * 128 + kin);
      const short* wb = &Wlds[k0h * 4096 + lane * 8];
#pragma unroll
      for (int n0 = 0; n0 < 8; ++n0) {
        bf16x8 b = *(const bf16x8*)(wb + n0 * 512);
        acc[0][n0] = __builtin_amdgcn_mfma_f32_16x16x32_bf16(a0, b, acc[0][n0], 0, 0, 0);
        acc[1][n0] = __builtin_amdgcn_mfma_f32_16x16x32_bf16(a1, b, acc[1][n0], 0, 0, 0);
      }
    }
  }
  int colb = lane & 15, rloc = kg * 4;
#pragma unroll
  for (int mt = 0; mt < 2; ++mt) {
    int rb = rowbase + mt * 16 + rloc;
#pragma unroll
    for (int n0 = 0; n0 < 8; ++n0) {
      int cc = n0 * 16 + colb;
      float bv = biasc[cc];
#pragma unroll
      for (int j = 0; j < 4; ++j) {
        int rr = rb + j;
        if (rr < N_NODES) {
          float v = acc[mt][n0][j] + bv;
          if (OUT_RELU_BF16) {
            ((short*)outp)[(size_t)rr * 128 + cc] = f2bf(v > 0.f ? v : 0.f);
          } else {
            ((float*)outp)[(size_t)rr * 128 + cc] = v;
          }
        }
      }
    }
  }
}

extern "C" void kernel_launch(void* const* d_in, const int* in_sizes, int n_in,
                              void* d_out, int out_size, void* d_ws, size_t ws_size,
                              hipStream_t stream) {
  (void)in_sizes; (void)n_in; (void)out_size; (void)ws_size;
  const float* xq  = (const float*)d_in[0];
  const float* xp  = (const float*)d_in[1];
  const int*   src = (const int*)d_in[2];
  const int*   dst = (const int*)d_in[3];
  const float* Ws1 = (const float*)d_in[4];
  const float* Wn1 = (const float*)d_in[5];
  const float* b1  = (const float*)d_in[6];
  const float* Ws2 = (const float*)d_in[7];
  const float* Wn2 = (const float*)d_in[8];
  const float* b2  = (const float*)d_in[9];

  char* w = (char*)d_ws;
  int*   cnt    = (int*)w;      w += (size_t)4 * N_NODES * 4;
  int*   bincnt = (int*)w;      w += 4096;
  int*   off    = (int*)w;      w += (size_t)4 * (N_NODES + 1) * 4;
  int*   csr    = (int*)w;      w += (size_t)4 * NEDGE * 4;
  short* meanA  = (short*)w;    w += (size_t)N_NODES * 128 * 2;
  short* meanB  = (short*)w;    w += (size_t)N_NODES * 128 * 2;
  short* h1q    = (short*)w;    w += (size_t)N_NODES * 128 * 2;
  short* h1p    = (short*)w;    w += (size_t)N_NODES * 128 * 2;
  short* xqb    = (short*)w;    w += (size_t)N_NODES * 128 * 2;
  short* xpb    = (short*)w;    w += (size_t)N_NODES * 128 * 2;
  short* WTp    = (short*)w;    w += (size_t)4 * 49152 * 2;
  float* biasc  = (float*)w;    w += 512 * 4;
  int*   bsum   = (int*)w;      w += 4 * 128 * 4;
  // staging is only live during CSR build, before meanA is first written:
  int2v* stage  = (int2v*)meanA;   // 4*196*3456*8B = 21.7MB <= 51.2MB (A+B)
  // type-1 mean buffers alias dead storage (fully overwritten before read):
  unsigned* mL1C = (unsigned*)d_out;                 // L1: d_out is scratch
  unsigned* mL1D = mL1C + (size_t)N_NODES * 64;
  unsigned* mL2C = (unsigned*)xqb;                   // L2: xqb/xpb are dead
  unsigned* mL2D = (unsigned*)xpb;

  dim3 b256(256);
  const int bgrid = (NEDGE + 2047) / 2048;        // 293
  const int ggrid = (N_NODES + 127) / 128;        // 782
  const int wgrid = 2 * N_NODES / 4;              // 50000 (wave per node+type)
  const int cgrid = (N_NODES * 16 + 255) / 256;   // 6250

  // --- CSR build via bucket counting-sort (no per-edge global atomics)
  hipMemsetAsync(bincnt, 0, 4096, stream);
  bin_k<<<dim3(bgrid, 4), b256, 0, stream>>>(src, dst, bincnt, stage);
  hist_k<<<dim3(NBUCK, 4), b256, 0, stream>>>(stage, bincnt, cnt);
  scan1_k<<<dim3(NBLK, 4), b256, 0, stream>>>(cnt, bsum);
  scan2_k<<<dim3(1), dim3(128), 0, stream>>>(bsum);
  scan3_k<<<dim3(NBLK, 4), b256, 0, stream>>>(cnt, bsum, off);
  place_k<<<dim3(NBUCK, 4), b256, 0, stream>>>(stage, bincnt, off, csr);
  prep_w_k<<<dim3(384), b256, 0, stream>>>(Ws1, Wn1, Ws2, Wn2, WTp);
  prep_b_k<<<dim3(2), b256, 0, stream>>>(b1, b2, biasc);
  cvt2_k<<<dim3(cgrid, 2), b256, 0, stream>>>(xq, xp, (unsigned*)xqb, (unsigned*)xpb);

  // ---- Layer 1: one gather (both types), one gemm (both types)
  gather2_k<<<wgrid, b256, 0, stream>>>((const unsigned*)xpb, (const unsigned*)xqb,
      csr, off, (unsigned*)meanA, (unsigned*)meanB, mL1C, mL1D);
  gemm2_k<1><<<dim3(ggrid, 2), b256, 0, stream>>>(
      xqb, xpb, meanA, meanB, (const short*)mL1C, (const short*)mL1D,
      WTp, biasc, h1q, h1p);

  // ---- Layer 2
  gather2_k<<<wgrid, b256, 0, stream>>>((const unsigned*)h1p, (const unsigned*)h1q,
      csr, off, (unsigned*)meanA, (unsigned*)meanB, mL2C, mL2D);
  gemm2_k<0><<<dim3(ggrid, 2), b256, 0, stream>>>(
      h1q, h1p, meanA, meanB, (const short*)mL2C, (const short*)mL2D,
      WTp + 2 * 49152, biasc + 256,
      (float*)d_out, (float*)d_out + (size_t)N_NODES * 128);
}